// Round 1
// baseline (283.315 us; speedup 1.0000x reference)
//
#include <hip/hip_runtime.h>
#include <hip/hip_bf16.h>

typedef _Float16 f16x8 __attribute__((ext_vector_type(8)));
typedef unsigned short u16x8 __attribute__((ext_vector_type(8)));
typedef float f32x4 __attribute__((ext_vector_type(4)));

static constexpr int Bn = 2;
static constexpr int Tn = 2048;
static constexpr int En = 1024;
static constexpr int Hn = 16;
static constexpr int Dn = 64;
#define LOG2E 1.44269504088896340736f

static constexpr int TS = 136;  // qkv epilogue transpose stride
static constexpr int PS = 40;   // attn P-chunk row stride (shorts): 20 dwords
                                // -> 16-lane b128 reads land 2-way (free, m136)

__device__ __forceinline__ unsigned short f2h(float x) {
  _Float16 h = (_Float16)x;
  return __builtin_bit_cast(unsigned short, h);
}
__device__ __forceinline__ float h2f(unsigned short u) {
  return (float)__builtin_bit_cast(_Float16, u);
}
__device__ __forceinline__ f16x8 ldh8(const unsigned short* p) {
  return __builtin_bit_cast(f16x8, *reinterpret_cast<const u16x8*>(p));
}
// async global->LDS, 16B/lane; LDS dest must be wave-uniform base (+lane*16)
__device__ __forceinline__ void gld16(const void* g, void* l) {
  __builtin_amdgcn_global_load_lds(
      (__attribute__((address_space(1))) void*)(const_cast<void*>(g)),
      (__attribute__((address_space(3))) void*)(l), 16, 0, 0);
}

// fp16 hi/lo split: (hi + lo) == x to ~22 mantissa bits
__global__ __launch_bounds__(256) void split_f32_f16(
    const float* __restrict__ src, unsigned short* __restrict__ hi,
    unsigned short* __restrict__ lo)
{
  const int i = (blockIdx.x * 256 + threadIdx.x) * 4;
  const float4 v = *reinterpret_cast<const float4*>(src + i);
  ushort4 h, l;
  h.x = f2h(v.x); l.x = f2h(v.x - h2f(h.x));
  h.y = f2h(v.y); l.y = f2h(v.y - h2f(h.y));
  h.z = f2h(v.z); l.z = f2h(v.z - h2f(h.z));
  h.w = f2h(v.w); l.w = f2h(v.w - h2f(h.w));
  *reinterpret_cast<ushort4*>(hi + i) = h;
  *reinterpret_cast<ushort4*>(lo + i) = l;
}

__global__ __launch_bounds__(256) void cvt_f32_f16(
    const float* __restrict__ src, unsigned short* __restrict__ dst)
{
  const int i = (blockIdx.x * 256 + threadIdx.x) * 4;
  const float4 v = *reinterpret_cast<const float4*>(src + i);
  ushort4 u;
  u.x = f2h(v.x); u.y = f2h(v.y); u.z = f2h(v.z); u.w = f2h(v.w);
  *reinterpret_cast<ushort4*>(dst + i) = u;
}

// QKV GEMM, fp16: A = x as fp16 hi+lo (exact), B = w_qkv fp16. Q/K: 2 MFMA,
// V: 1 MFMA. Permuted column tiling c' = kk*1024 + hh*64 + dd
// (w_qkv row n = dd*48+kk*16+hh). Outputs fp16: Q(x8),K [b,h,t,d]; V [b,h,d,t].
__global__ __launch_bounds__(256) void gemm_qkv(
    const unsigned short* __restrict__ xh, const unsigned short* __restrict__ xl,
    const unsigned short* __restrict__ wf,
    unsigned short* __restrict__ Qf, unsigned short* __restrict__ Kf,
    unsigned short* __restrict__ Vf, int M, int K)
{
  __shared__ unsigned short smem[128 * TS];  // 34816 B; reused by epilogue
  unsigned short* shAh = smem;               // 128x32 each, unpadded
  unsigned short* shAl = smem + 4096;
  unsigned short* shB = smem + 8192;

  const int tid = threadIdx.x;
  const int w = tid >> 6, L = tid & 63, qd = L >> 4, lr = L & 15;
  const int m0 = blockIdx.y * 128;
  const int kk = blockIdx.x >> 3;          // 0=Q 1=K 2=V (uniform per block)
  const int hh0 = (blockIdx.x & 7) * 2;    // two heads per block
  const int wm = (w >> 1) * 64, wn = (w & 1) * 64;

  f32x4 acc[4][4] = {};

  for (int k0 = 0; k0 < K; k0 += 32) {
#pragma unroll
    for (int p = 0; p < 2; ++p) {
      const int c = p * 256 + tid;
      const int row = c >> 2, slot = c & 3;
      const int dd = row & 63, hl = row >> 6;
      const int nB = dd * 48 + kk * 16 + hh0 + hl;
      const size_t aoff = (size_t)(m0 + row) * K + k0 + slot * 8;
      const size_t boff = (size_t)nB * K + k0 + slot * 8;
      const int base = (p * 4 + w) * 512;  // wave-uniform LDS base (shorts)
      gld16(xh + aoff, &shAh[base]);
      gld16(wf + boff, &shB[base]);
      if (kk < 2) gld16(xl + aoff, &shAl[base]);
    }
    __syncthreads();

    f16x8 afh[4], bf[4];
#pragma unroll
    for (int mt = 0; mt < 4; ++mt)
      afh[mt] = ldh8(&shAh[(wm + mt * 16 + lr) * 32 + qd * 8]);
#pragma unroll
    for (int nt = 0; nt < 4; ++nt)
      bf[nt] = ldh8(&shB[(wn + nt * 16 + lr) * 32 + qd * 8]);
    if (kk < 2) {
      f16x8 afl[4];
#pragma unroll
      for (int mt = 0; mt < 4; ++mt)
        afl[mt] = ldh8(&shAl[(wm + mt * 16 + lr) * 32 + qd * 8]);
#pragma unroll
      for (int mt = 0; mt < 4; ++mt)
#pragma unroll
        for (int nt = 0; nt < 4; ++nt) {
          acc[mt][nt] = __builtin_amdgcn_mfma_f32_16x16x32_f16(afh[mt], bf[nt], acc[mt][nt], 0, 0, 0);
          acc[mt][nt] = __builtin_amdgcn_mfma_f32_16x16x32_f16(afl[mt], bf[nt], acc[mt][nt], 0, 0, 0);
        }
    } else {
#pragma unroll
      for (int mt = 0; mt < 4; ++mt)
#pragma unroll
        for (int nt = 0; nt < 4; ++nt)
          acc[mt][nt] = __builtin_amdgcn_mfma_f32_16x16x32_f16(afh[mt], bf[nt], acc[mt][nt], 0, 0, 0);
    }
    __syncthreads();
  }

  // epilogue: fp16 into LDS transpose buffer -> coalesced 16B stores
  const int b = m0 >> 11;
  const int t0 = m0 & (Tn - 1);
  const float qscale = (kk == 0) ? 8.0f : 1.0f;  // fold *sqrt(d) into Q
#pragma unroll
  for (int mt = 0; mt < 4; ++mt)
#pragma unroll
    for (int nt = 0; nt < 4; ++nt)
#pragma unroll
      for (int r = 0; r < 4; ++r) {
        const int ml = wm + mt * 16 + qd * 4 + r;  // C/D row=(lane>>4)*4+reg
        const int cl = wn + nt * 16 + lr;          // C/D col=lane&15
        smem[ml * TS + cl] = f2h(acc[mt][nt][r] * qscale);
      }
  __syncthreads();

  unsigned short* dst = (kk == 0) ? Qf : (kk == 1) ? Kf : Vf;
  if (kk < 2) {
#pragma unroll
    for (int p = 0; p < 8; ++p) {
      const int s = p * 256 + tid;
      const int tl = s >> 4, sub = s & 15;
      const int hl = sub >> 3, oct = sub & 7;
      const u16x8 v = *reinterpret_cast<const u16x8*>(&smem[tl * TS + hl * 64 + oct * 8]);
      *reinterpret_cast<u16x8*>(
          dst + ((size_t)(b * Hn + hh0 + hl) * Tn + t0 + tl) * Dn + oct * 8) = v;
    }
  } else {
#pragma unroll
    for (int p = 0; p < 8; ++p) {
      const int s = p * 256 + tid;
      const int cl = s >> 4, oct = s & 15;
      const int hl = cl >> 6, dd = cl & 63;
      u16x8 v;
#pragma unroll
      for (int j = 0; j < 8; ++j) v[j] = smem[(oct * 8 + j) * TS + cl];
      *reinterpret_cast<u16x8*>(
          dst + ((size_t)((b * Hn + hh0 + hl) * Dn + dd)) * Tn + t0 + oct * 8) = v;
    }
  }
}

// Flash attention, fp16 energy, j-tile 128, chunked P (small LDS), row-sum via
// MFMA ones-trick. THIS ROUND: each wave owns 2 m-tiles (32 q-rows) so every
// K/V fragment read from LDS feeds 2 MFMAs; block covers 128 q-rows, halving
// K/V global re-fetch and staging per unit work.
// Qf(x8),Kf: [b,h,t,d]  Vf: [b,h,d,t]  AO: fp16.
__global__ __launch_bounds__(256) void attn_kernel(
    const unsigned short* __restrict__ Qf, const unsigned short* __restrict__ Kf,
    const unsigned short* __restrict__ Vf, unsigned short* __restrict__ AOf)
{
  __shared__ unsigned short shK[2 * 128 * 32];  // [kc][j row][32]  16 KB
  __shared__ unsigned short shV[4 * 64 * 32];   // [kcv][dd][32]    16 KB
  __shared__ unsigned short shP[8 * 16 * PS];   // per-(wave,mt) 16x32, 10 KB
  const int tid = threadIdx.x;
  const int w = tid >> 6, L = tid & 63, qd = L >> 4, lr = L & 15;
  const int q0 = blockIdx.x * 128;
  const int bh = blockIdx.y;

  f16x8 aq[2][2];
#pragma unroll
  for (int mt = 0; mt < 2; ++mt) {
    const size_t qoff = ((size_t)bh * Tn + q0 + w * 32 + mt * 16 + lr) * Dn;
    aq[mt][0] = ldh8(Qf + qoff + qd * 8);
    aq[mt][1] = ldh8(Qf + qoff + 32 + qd * 8);
  }
  f16x8 ones;
#pragma unroll
  for (int j = 0; j < 8; ++j) ones[j] = (_Float16)1.0f;

  f32x4 oacc[2][4] = {};
  float mrow[2][4], lsum[2][4];
#pragma unroll
  for (int mt = 0; mt < 2; ++mt)
#pragma unroll
    for (int r = 0; r < 4; ++r) { mrow[mt][r] = -1e30f; lsum[mt][r] = 0.f; }

  for (int j0 = 0; j0 < Tn; j0 += 128) {
    // stage K tile (128 j x 64 d) as [kc][row][32]
#pragma unroll
    for (int p = 0; p < 4; ++p) {
      const int kc = p >> 1, half = p & 1;
      const int row = half * 64 + (tid >> 2);
      const int slot = tid & 3;
      gld16(Kf + ((size_t)bh * Tn + j0 + row) * Dn + kc * 32 + slot * 8,
            &shK[kc * 4096 + (half * 64 + w * 16) * 32]);
    }
    // stage V tile (64 d x 128 t) as [kcv][dd][32]
#pragma unroll
    for (int p = 0; p < 4; ++p) {
      const int dd = tid >> 2, slot = tid & 3;
      gld16(Vf + ((size_t)bh * Dn + dd) * Tn + j0 + p * 32 + slot * 8,
            &shV[p * 2048 + (w * 16) * 32]);
    }
    __syncthreads();

    // S = Q K^T (Q pre-scaled by 8): 8 col-blocks of 16; each K frag -> 2 MFMA
    f32x4 s2[2][8];
#pragma unroll
    for (int ct = 0; ct < 8; ++ct) {
      s2[0][ct] = f32x4{0.f, 0.f, 0.f, 0.f};
      s2[1][ct] = f32x4{0.f, 0.f, 0.f, 0.f};
      const int rk = ct * 16 + lr;
#pragma unroll
      for (int kc = 0; kc < 2; ++kc) {
        const f16x8 bk = ldh8(&shK[kc * 4096 + rk * 32 + qd * 8]);
        s2[0][ct] = __builtin_amdgcn_mfma_f32_16x16x32_f16(aq[0][kc], bk, s2[0][ct], 0, 0, 0);
        s2[1][ct] = __builtin_amdgcn_mfma_f32_16x16x32_f16(aq[1][kc], bk, s2[1][ct], 0, 0, 0);
      }
    }

    // row max over 128 cols (only remaining shfl reduction)
    float tmax[2][4];
#pragma unroll
    for (int mt = 0; mt < 2; ++mt)
#pragma unroll
      for (int r = 0; r < 4; ++r) {
        tmax[mt][r] = s2[mt][0][r];
#pragma unroll
        for (int ct = 1; ct < 8; ++ct) tmax[mt][r] = fmaxf(tmax[mt][r], s2[mt][ct][r]);
      }
#pragma unroll
    for (int x = 1; x < 16; x <<= 1)
#pragma unroll
      for (int mt = 0; mt < 2; ++mt)
#pragma unroll
        for (int r = 0; r < 4; ++r)
          tmax[mt][r] = fmaxf(tmax[mt][r], __shfl_xor(tmax[mt][r], x, 64));

    float alpha[2][4];
#pragma unroll
    for (int mt = 0; mt < 2; ++mt)
#pragma unroll
      for (int r = 0; r < 4; ++r) {
        const float mn = fmaxf(mrow[mt][r], tmax[mt][r]);
        alpha[mt][r] = exp2f((mrow[mt][r] - mn) * LOG2E);
        mrow[mt][r] = mn;
      }
#pragma unroll
    for (int mt = 0; mt < 2; ++mt)
#pragma unroll
      for (int ct = 0; ct < 8; ++ct)
#pragma unroll
        for (int r = 0; r < 4; ++r)
          s2[mt][ct][r] = exp2f((s2[mt][ct][r] - mrow[mt][r]) * LOG2E);  // arg <= 0
#pragma unroll
    for (int mt = 0; mt < 2; ++mt)
#pragma unroll
      for (int nt = 0; nt < 4; ++nt)
#pragma unroll
        for (int r = 0; r < 4; ++r) oacc[mt][nt][r] *= alpha[mt][r];

    // chunked P: per 32-col chunk, C-layout -> LDS -> A-layout, PV + sum MFMA.
    // V fragment read once, used by both m-tiles.
    f32x4 sacc[2] = {};
#pragma unroll
    for (int kcv = 0; kcv < 4; ++kcv) {
#pragma unroll
      for (int mt = 0; mt < 2; ++mt) {
        unsigned short* myP = &shP[(w * 2 + mt) * 16 * PS];
#pragma unroll
        for (int ct2 = 0; ct2 < 2; ++ct2)
#pragma unroll
          for (int r = 0; r < 4; ++r)
            myP[(qd * 4 + r) * PS + ct2 * 16 + lr] = f2h(s2[mt][kcv * 2 + ct2][r]);
      }
      f16x8 pa[2];
#pragma unroll
      for (int mt = 0; mt < 2; ++mt)
        pa[mt] = ldh8(&shP[(w * 2 + mt) * 16 * PS + lr * PS + qd * 8]);
#pragma unroll
      for (int nt = 0; nt < 4; ++nt) {
        const f16x8 bv = ldh8(&shV[kcv * 2048 + (nt * 16 + lr) * 32 + qd * 8]);
        oacc[0][nt] = __builtin_amdgcn_mfma_f32_16x16x32_f16(pa[0], bv, oacc[0][nt], 0, 0, 0);
        oacc[1][nt] = __builtin_amdgcn_mfma_f32_16x16x32_f16(pa[1], bv, oacc[1][nt], 0, 0, 0);
      }
      sacc[0] = __builtin_amdgcn_mfma_f32_16x16x32_f16(pa[0], ones, sacc[0], 0, 0, 0);
      sacc[1] = __builtin_amdgcn_mfma_f32_16x16x32_f16(pa[1], ones, sacc[1], 0, 0, 0);
    }
#pragma unroll
    for (int mt = 0; mt < 2; ++mt)
#pragma unroll
      for (int r = 0; r < 4; ++r)
        lsum[mt][r] = lsum[mt][r] * alpha[mt][r] + sacc[mt][r];
    __syncthreads();
  }

  const int b = bh >> 4, h = bh & 15;
#pragma unroll
  for (int mt = 0; mt < 2; ++mt)
#pragma unroll
    for (int nt = 0; nt < 4; ++nt)
#pragma unroll
      for (int r = 0; r < 4; ++r) {
        const int trow = q0 + w * 32 + mt * 16 + qd * 4 + r;
        const int col = h * 64 + nt * 16 + lr;
        AOf[((size_t)b * Tn + trow) * En + col] = f2h(oacc[mt][nt][r] / lsum[mt][r]);
      }
}

// Out-projection: OUT f32; A = AO fp16, B = wout fp16 (pre-cast).
__global__ __launch_bounds__(256) void gemm_out(
    const unsigned short* __restrict__ A, const unsigned short* __restrict__ Bm,
    float* __restrict__ C, int M, int N, int K)
{
  __shared__ unsigned short shA[128 * 32];
  __shared__ unsigned short shB[128 * 32];
  const int tid = threadIdx.x;
  const int w = tid >> 6, L = tid & 63, qd = L >> 4, lr = L & 15;
  const int m0 = blockIdx.y * 128;
  const int n0 = blockIdx.x * 128;
  const int wm = (w >> 1) * 64, wn = (w & 1) * 64;

  f32x4 acc[4][4] = {};

  for (int k0 = 0; k0 < K; k0 += 32) {
#pragma unroll
    for (int p = 0; p < 2; ++p) {
      const int c = p * 256 + tid;
      const int row = c >> 2, slot = c & 3;
      const int base = (p * 4 + w) * 512;
      gld16(A + (size_t)(m0 + row) * K + k0 + slot * 8, &shA[base]);
      gld16(Bm + (size_t)(n0 + row) * K + k0 + slot * 8, &shB[base]);
    }
    __syncthreads();

    f16x8 af[4], bf[4];
#pragma unroll
    for (int mt = 0; mt < 4; ++mt)
      af[mt] = ldh8(&shA[(wm + mt * 16 + lr) * 32 + qd * 8]);
#pragma unroll
    for (int nt = 0; nt < 4; ++nt)
      bf[nt] = ldh8(&shB[(wn + nt * 16 + lr) * 32 + qd * 8]);
#pragma unroll
    for (int mt = 0; mt < 4; ++mt)
#pragma unroll
      for (int nt = 0; nt < 4; ++nt)
        acc[mt][nt] = __builtin_amdgcn_mfma_f32_16x16x32_f16(af[mt], bf[nt], acc[mt][nt], 0, 0, 0);
    __syncthreads();
  }

#pragma unroll
  for (int mt = 0; mt < 4; ++mt)
#pragma unroll
    for (int nt = 0; nt < 4; ++nt)
#pragma unroll
      for (int r = 0; r < 4; ++r) {
        const int m = m0 + wm + mt * 16 + qd * 4 + r;
        const int n = n0 + wn + nt * 16 + lr;
        C[(size_t)m * N + n] = acc[mt][nt][r];
      }
}

extern "C" void kernel_launch(void* const* d_in, const int* in_sizes, int n_in,
                              void* d_out, int out_size, void* d_ws, size_t ws_size,
                              hipStream_t stream) {
  (void)in_sizes; (void)n_in; (void)out_size; (void)ws_size;
  const float* x = (const float*)d_in[0];      // [2,2048,1024] f32
  const float* wqkv = (const float*)d_in[1];   // [3072,1024]  f32
  const float* wout = (const float*)d_in[2];   // [1024,1024]  f32
  float* out = (float*)d_out;                  // [2,2048,1024] f32

  const size_t elems = (size_t)Bn * Hn * Tn * Dn;  // 4M elems (8 MiB fp16)
  unsigned short* Qf = (unsigned short*)d_ws;
  unsigned short* Kf = Qf + elems;
  unsigned short* Vf = Kf + elems;
  unsigned short* AOf = Vf + elems;
  unsigned short* wf = AOf + elems;                // fp16 w_qkv, 3M
  unsigned short* wof = wf + (size_t)3 * En * En;  // fp16 wout, 1M (40 MiB)

  // d_out (16 MiB) doubles as scratch for x hi/lo; overwritten by gemm_out.
  unsigned short* xh = (unsigned short*)d_out;
  unsigned short* xl = xh + elems;

  const int M = Bn * Tn;  // 4096
  dim3 blk(256);
  split_f32_f16<<<dim3((int)(elems / 1024)), blk, 0, stream>>>(x, xh, xl);
  cvt_f32_f16<<<dim3(3 * En * En / 1024), blk, 0, stream>>>(wqkv, wf);
  cvt_f32_f16<<<dim3(En * En / 1024), blk, 0, stream>>>(wout, wof);
  gemm_qkv<<<dim3(24, M / 128), blk, 0, stream>>>(
      xh, xl, wf, Qf, Kf, Vf, M, En);
  attn_kernel<<<dim3(Tn / 128, Bn * Hn), blk, 0, stream>>>(Qf, Kf, Vf, AOf);
  gemm_out<<<dim3(En / 128, M / 128), blk, 0, stream>>>(
      AOf, wof, out, M, En, En);
}